// Round 4
// baseline (123.763 us; speedup 1.0000x reference)
//
#include <hip/hip_runtime.h>

typedef __bf16 bf16_t;
typedef bf16_t bf16x8 __attribute__((ext_vector_type(8)));
typedef bf16_t bf16x4 __attribute__((ext_vector_type(4)));
typedef float f32x4 __attribute__((ext_vector_type(4)));

// ---------------- fp32 -> bf16 convert, all three tensors in one launch ----------------
// ranges (float4 units): x 98304 | w_qkv 442368 | w_proj 147456  (total 688128 = 2688*256)
__global__ void f2b_all(const float* __restrict__ x, const float* __restrict__ wq,
                        const float* __restrict__ wp,
                        bf16_t* __restrict__ xb, bf16_t* __restrict__ wqb,
                        bf16_t* __restrict__ wpb) {
    int i = blockIdx.x * blockDim.x + threadIdx.x;
    const float* src; bf16_t* dst; int off;
    if (i < 98304)       { src = x;  dst = xb;  off = i; }
    else if (i < 540672) { src = wq; dst = wqb; off = i - 98304; }
    else                 { src = wp; dst = wpb; off = i - 540672; }
    f32x4 v = reinterpret_cast<const f32x4*>(src)[off];
    bf16x4 o = { (bf16_t)v[0], (bf16_t)v[1], (bf16_t)v[2], (bf16_t)v[3] };
    reinterpret_cast<bf16x4*>(dst)[off] = o;
}

// ---------------- bf16 GEMM: C = A * B^T (+bias), 64x64 tile, BK=64, padded LDS ----------------
template <typename OUT_T, bool HAS_BIAS>
__global__ __launch_bounds__(256) void gemm_bt(
    const bf16_t* __restrict__ A, const bf16_t* __restrict__ B,
    OUT_T* __restrict__ C, const float* __restrict__ bias,
    int K, int lda, int ldb, int ldc)
{
    const int m0 = blockIdx.x * 64;
    const int n0 = blockIdx.y * 64;

    __shared__ __align__(16) bf16_t As[64][72];
    __shared__ __align__(16) bf16_t Bs[64][72];

    const int tid  = threadIdx.x;
    const int lane = tid & 63;
    const int wave = tid >> 6;

    f32x4 acc[4] = {};

    for (int k0 = 0; k0 < K; k0 += 64) {
#pragma unroll
        for (int c = 0; c < 2; ++c) {
            const int chunk = c * 256 + tid;
            const int row = chunk >> 3;
            const int off = (chunk & 7) * 8;
            *reinterpret_cast<uint4*>(&As[row][off]) =
                *reinterpret_cast<const uint4*>(&A[(long)(m0 + row) * lda + k0 + off]);
            *reinterpret_cast<uint4*>(&Bs[row][off]) =
                *reinterpret_cast<const uint4*>(&B[(long)(n0 + row) * ldb + k0 + off]);
        }
        __syncthreads();
#pragma unroll
        for (int ks = 0; ks < 64; ks += 32) {
            bf16x8 af = *reinterpret_cast<const bf16x8*>(&As[wave * 16 + (lane & 15)][(lane >> 4) * 8 + ks]);
#pragma unroll
            for (int nf = 0; nf < 4; ++nf) {
                bf16x8 bfr = *reinterpret_cast<const bf16x8*>(&Bs[nf * 16 + (lane & 15)][(lane >> 4) * 8 + ks]);
                acc[nf] = __builtin_amdgcn_mfma_f32_16x16x32_bf16(af, bfr, acc[nf], 0, 0, 0);
            }
        }
        __syncthreads();
    }

    const int crow0 = m0 + wave * 16 + (lane >> 4) * 4;
    const int ccol0 = n0 + (lane & 15);
#pragma unroll
    for (int nf = 0; nf < 4; ++nf) {
        const int col = ccol0 + nf * 16;
        const float bv = HAS_BIAS ? bias[col] : 0.0f;
#pragma unroll
        for (int v = 0; v < 4; ++v) {
            C[(long)(crow0 + v) * ldc + col] = (OUT_T)(acc[nf][v] + bv);
        }
    }
}

// ---------------- fused S = softmax((q/8) k^T): one block = 64 rows x 256 cols of one (b,h) ----------------
__global__ __launch_bounds__(256) void qk_softmax(
    const bf16_t* __restrict__ qkv,   // [B,256,2304]
    float* __restrict__ probs)        // [24,256,256]
{
    const int bh = blockIdx.y;                 // b*12 + h
    const int b = bh / 12, h = bh % 12;
    const int m0 = blockIdx.x * 64;
    const bf16_t* qbase = qkv + (long)b * 589824 + h * 64;
    const bf16_t* kbase = qkv + (long)b * 589824 + 768 + h * 64;

    __shared__ __align__(16) bf16_t Qs[64][72];
    __shared__ __align__(16) bf16_t Ks[256][72];

    const int t = threadIdx.x;
#pragma unroll
    for (int c = 0; c < 2; ++c) {
        const int chunk = c * 256 + t;
        const int row = chunk >> 3, off = (chunk & 7) * 8;
        *reinterpret_cast<uint4*>(&Qs[row][off]) =
            *reinterpret_cast<const uint4*>(qbase + (long)(m0 + row) * 2304 + off);
    }
#pragma unroll
    for (int c = 0; c < 8; ++c) {
        const int chunk = c * 256 + t;
        const int row = chunk >> 3, off = (chunk & 7) * 8;
        *reinterpret_cast<uint4*>(&Ks[row][off]) =
            *reinterpret_cast<const uint4*>(kbase + (long)row * 2304 + off);
    }
    __syncthreads();

    const int lane = t & 63, wave = t >> 6;
    f32x4 acc[16] = {};
#pragma unroll
    for (int ks = 0; ks < 64; ks += 32) {
        bf16x8 af = *reinterpret_cast<const bf16x8*>(&Qs[wave * 16 + (lane & 15)][(lane >> 4) * 8 + ks]);
#pragma unroll
        for (int nf = 0; nf < 16; ++nf) {
            bf16x8 bfr = *reinterpret_cast<const bf16x8*>(&Ks[nf * 16 + (lane & 15)][(lane >> 4) * 8 + ks]);
            acc[nf] = __builtin_amdgcn_mfma_f32_16x16x32_bf16(af, bfr, acc[nf], 0, 0, 0);
        }
    }

    float inv[4];
#pragma unroll
    for (int v = 0; v < 4; ++v) {
        float mm = -1e30f;
#pragma unroll
        for (int nf = 0; nf < 16; ++nf) { acc[nf][v] *= 0.125f; mm = fmaxf(mm, acc[nf][v]); }
#pragma unroll
        for (int o = 1; o < 16; o <<= 1) mm = fmaxf(mm, __shfl_xor(mm, o));
        float s = 0.0f;
#pragma unroll
        for (int nf = 0; nf < 16; ++nf) { float e = __expf(acc[nf][v] - mm); acc[nf][v] = e; s += e; }
#pragma unroll
        for (int o = 1; o < 16; o <<= 1) s += __shfl_xor(s, o);
        inv[v] = 1.0f / s;
    }

    float* prow = probs + ((long)bh * 256 + m0 + wave * 16 + (lane >> 4) * 4) * 256 + (lane & 15);
#pragma unroll
    for (int nf = 0; nf < 16; ++nf) {
#pragma unroll
        for (int v = 0; v < 4; ++v) {
            prow[(long)v * 256 + nf * 16] = acc[nf][v] * inv[v];
        }
    }
}

// ---------------- fused: oh[b,i,c] = sum_j attn[b,h(c),i,j] * (v[b,j,c] + d[b,i,j,c]) ----------------
// One block per (b,i): 1024 threads = 16 waves. Wave w streams 16 consecutive j-rows
// (each 3KB row = 3 contiguous 1KB wave-loads, nontemporal). LDS partial reduce at end.
__global__ __launch_bounds__(1024) void attnd_kernel(
    const float* __restrict__ attn,   // [24,256,256] fp32 probs
    const bf16_t* __restrict__ qkv,   // [B,256,2304]
    const float* __restrict__ d,      // [B,256,256,768]
    bf16_t* __restrict__ oh)          // [B,256,768]
{
    const int bi = blockIdx.x;          // b*256 + i
    const int b  = bi >> 8;
    const int i  = bi & 255;
    const int t  = threadIdx.x;
    const int lane = t & 63, wave = t >> 6;

    __shared__ float attn_s[12 * 257];          // 12 heads x 256 j, padded
    __shared__ float pw[16][768];               // per-wave partials

#pragma unroll
    for (int it = 0; it < 3; ++it) {
        const int idx = it * 1024 + t;
        const int h = idx >> 8, j = idx & 255;
        attn_s[h * 257 + j] = attn[(((long)(b * 12 + h)) * 256 + i) * 256 + j];
    }
    __syncthreads();

    const int h0 = lane >> 4;                   // head-within-segment
    const float* dbase = d + (long)bi * 196608 + lane * 4;
    const bf16_t* vbase = qkv + (long)b * 589824 + 1536 + lane * 4;
    const float* a0p = attn_s + (0 + h0) * 257;
    const float* a1p = attn_s + (4 + h0) * 257;
    const float* a2p = attn_s + (8 + h0) * 257;

    f32x4 acc0 = {}, acc1 = {}, acc2 = {};
#pragma unroll 4
    for (int jj = 0; jj < 16; ++jj) {
        const int j = wave * 16 + jj;
        const float* dr = dbase + (long)j * 768;
        const bf16_t* vr = vbase + (long)j * 2304;
        f32x4 d0 = __builtin_nontemporal_load(reinterpret_cast<const f32x4*>(dr));
        f32x4 d1 = __builtin_nontemporal_load(reinterpret_cast<const f32x4*>(dr + 256));
        f32x4 d2 = __builtin_nontemporal_load(reinterpret_cast<const f32x4*>(dr + 512));
        bf16x4 v0 = *reinterpret_cast<const bf16x4*>(vr);
        bf16x4 v1 = *reinterpret_cast<const bf16x4*>(vr + 256);
        bf16x4 v2 = *reinterpret_cast<const bf16x4*>(vr + 512);
        const float a0 = a0p[j], a1 = a1p[j], a2 = a2p[j];
#pragma unroll
        for (int e = 0; e < 4; ++e) {
            acc0[e] = fmaf(a0, d0[e] + (float)v0[e], acc0[e]);
            acc1[e] = fmaf(a1, d1[e] + (float)v1[e], acc1[e]);
            acc2[e] = fmaf(a2, d2[e] + (float)v2[e], acc2[e]);
        }
    }

    *reinterpret_cast<f32x4*>(&pw[wave][lane * 4])       = acc0;
    *reinterpret_cast<f32x4*>(&pw[wave][256 + lane * 4]) = acc1;
    *reinterpret_cast<f32x4*>(&pw[wave][512 + lane * 4]) = acc2;
    __syncthreads();

    if (t < 768) {
        float s = 0.0f;
#pragma unroll
        for (int w = 0; w < 16; ++w) s += pw[w][t];
        oh[(long)bi * 768 + t] = (bf16_t)s;
    }
}

// ---------------- launch ----------------
extern "C" void kernel_launch(void* const* d_in, const int* in_sizes, int n_in,
                              void* d_out, int out_size, void* d_ws, size_t ws_size,
                              hipStream_t stream) {
    const float* x      = (const float*)d_in[0];   // [2,256,768]
    const float* d      = (const float*)d_in[1];   // [2,256,256,768]
    const float* w_qkv  = (const float*)d_in[2];   // [2304,768]
    const float* w_proj = (const float*)d_in[3];   // [768,768]
    const float* b_proj = (const float*)d_in[4];   // [768]
    float* out = (float*)d_out;                    // [2,256,768]

    char* ws = (char*)d_ws;
    bf16_t* xb    = (bf16_t*)(ws);                  //  512x768
    bf16_t* wqb   = (bf16_t*)(ws + 786432);         // 2304x768
    bf16_t* wpb   = (bf16_t*)(ws + 4325376);        //  768x768
    bf16_t* qkvb  = (bf16_t*)(ws + 5505024);        //  512x2304
    float*  probs = (float*)(ws + 7864320);         //  24x256x256 fp32
    bf16_t* oh    = (bf16_t*)(ws + 14155776);       //  512x768

    // 1. converts
    f2b_all<<<2688, 256, 0, stream>>>(x, w_qkv, w_proj, xb, wqb, wpb);

    // 2. qkv = x @ w_qkv^T -> bf16 [512,2304]
    gemm_bt<bf16_t, false><<<dim3(8, 36), 256, 0, stream>>>(
        xb, wqb, qkvb, nullptr, 768, 768, 768, 2304);

    // 3. probs = softmax((q/8) k^T) -> fp32 [24,256,256]
    qk_softmax<<<dim3(4, 24), 256, 0, stream>>>(qkvb, probs);

    // 4. oh = attn @ (v + d_pair) -> bf16 [512,768]
    attnd_kernel<<<512, 1024, 0, stream>>>(probs, qkvb, d, oh);

    // 5. out = oh @ w_proj^T + b_proj -> fp32
    gemm_bt<float, true><<<dim3(8, 12), 256, 0, stream>>>(
        oh, wpb, out, b_proj, 768, 768, 768, 768);
}